// Round 5
// baseline (176.168 us; speedup 1.0000x reference)
//
#include <hip/hip_runtime.h>
#include <hip/hip_bf16.h>

#define J_JOINTS 17
#define ROW_F 51        // floats per row per array
#define BLOCK 256

// Each thread owns 4 rows = 204 floats = 51 float4 per array (16B-aligned).
// 3 float4 = 12 floats = 4 joints exactly; 17 units of 3 float4 per group.

__global__ __launch_bounds__(BLOCK, 4) void loss_main_kernel(
    const float* __restrict__ outp,   // (B, 17, 3)
    const float* __restrict__ tgt,    // (B, 17, 3)
    double* __restrict__ acc,         // acc[0]=cls_sum, acc[1]=reg_sum
    int B)
{
    const int tid = threadIdx.x;
    const int g   = blockIdx.x * BLOCK + tid;   // group index (4 rows)
    const int ngroups = B >> 2;

    float cls_acc = 0.0f;
    float reg_acc = 0.0f;

    if (g < ngroups) {
        const float4* O = reinterpret_cast<const float4*>(outp) + g * ROW_F;
        const float4* T = reinterpret_cast<const float4*>(tgt)  + g * ROW_F;

        float sq[4] = {0.f, 0.f, 0.f, 0.f};
        float nj[4] = {0.f, 0.f, 0.f, 0.f};

        #pragma unroll
        for (int u = 0; u < 17; ++u) {
            const float4 a0 = O[3*u + 0];
            const float4 a1 = O[3*u + 1];
            const float4 a2 = O[3*u + 2];
            const float4 b0 = T[3*u + 0];
            const float4 b1 = T[3*u + 1];
            const float4 b2 = T[3*u + 2];

            const float ox[4] = {a0.x, a0.w, a1.z, a2.y};
            const float oy[4] = {a0.y, a1.x, a1.w, a2.z};
            const float oz[4] = {a0.z, a1.y, a2.x, a2.w};
            const float tx[4] = {b0.x, b0.w, b1.z, b2.y};
            const float ty[4] = {b0.y, b1.x, b1.w, b2.z};
            const float tz[4] = {b0.z, b1.y, b2.x, b2.w};

            #pragma unroll
            for (int jj = 0; jj < 4; ++jj) {
                const int joint = 4*u + jj;     // 0..67, compile-time
                const int r = joint / 17;       // row within group, compile-time

                const bool gt1 = (tz[jj] == 1.0f);
                cls_acc += fmaxf(__logf(gt1 ? oz[jj] : (1.0f - oz[jj])), -100.0f);

                const bool keep = (oz[jj] >= 0.5f);
                const float d0 = keep ? (ox[jj] - tx[jj]) : 0.0f;
                const float d1 = keep ? (oy[jj] - ty[jj]) : 0.0f;
                sq[r] = fmaf(d0, d0, fmaf(d1, d1, sq[r]));
                nj[r] += gt1 ? 1.0f : 0.0f;
            }
        }

        #pragma unroll
        for (int r = 0; r < 4; ++r) {
            reg_acc += __fdividef(0.5f * sq[r], 1.0f + nj[r]);
        }
    }

    // generic tail rows (B % 4 != 0): handled scalar by block 0
    const int tail0 = ngroups << 2;
    if (blockIdx.x == 0 && tid < (B - tail0)) {
        const int b = tail0 + tid;
        float sq = 0.f, nj = 0.f;
        for (int j = 0; j < J_JOINTS; ++j) {
            const int base = b * ROW_F + 3*j;
            const float ox = outp[base + 0];
            const float oy = outp[base + 1];
            const float oz = outp[base + 2];
            const float tx = tgt[base + 0];
            const float ty = tgt[base + 1];
            const float tz = tgt[base + 2];
            const bool gt1 = (tz == 1.0f);
            cls_acc += fmaxf(__logf(gt1 ? oz : (1.0f - oz)), -100.0f);
            const bool keep = (oz >= 0.5f);
            const float d0 = keep ? (ox - tx) : 0.0f;
            const float d1 = keep ? (oy - ty) : 0.0f;
            sq = fmaf(d0, d0, fmaf(d1, d1, sq));
            nj += gt1 ? 1.0f : 0.0f;
        }
        reg_acc += __fdividef(0.5f * sq, 1.0f + nj);
    }

    // ---- block reduction (cold path) ----
    #pragma unroll
    for (int m = 1; m < 64; m <<= 1) {
        cls_acc += __shfl_xor(cls_acc, m, 64);
        reg_acc += __shfl_xor(reg_acc, m, 64);
    }
    __shared__ float s_cls[BLOCK / 64];
    __shared__ float s_reg[BLOCK / 64];
    const int wid = tid >> 6;
    if ((tid & 63) == 0) {
        s_cls[wid] = cls_acc;
        s_reg[wid] = reg_acc;
    }
    __syncthreads();
    if (tid == 0) {
        float c = 0.0f, r = 0.0f;
        #pragma unroll
        for (int w = 0; w < BLOCK / 64; ++w) { c += s_cls[w]; r += s_reg[w]; }
        atomicAdd(&acc[0], (double)c);
        atomicAdd(&acc[1], (double)r);
    }
}

__global__ void loss_finalize_kernel(const double* __restrict__ acc,
                                     float* __restrict__ out, int B)
{
    const double cls_sum = acc[0];
    const double reg_sum = acc[1];
    const double loss_class = -cls_sum / ((double)B * (double)J_JOINTS);
    const double loss_reg   = reg_sum / (double)B;
    out[0] = (float)(loss_class + loss_reg);
}

extern "C" void kernel_launch(void* const* d_in, const int* in_sizes, int n_in,
                              void* d_out, int out_size, void* d_ws, size_t ws_size,
                              hipStream_t stream) {
    const float* outp = (const float*)d_in[0];
    const float* tgt  = (const float*)d_in[1];
    float* out = (float*)d_out;
    const int B = in_sizes[0] / (J_JOINTS * 3);

    double* acc = (double*)d_ws;
    hipMemsetAsync(acc, 0, 2 * sizeof(double), stream);

    const int ngroups = B >> 2;
    const int blocks = (ngroups + BLOCK - 1) / BLOCK;   // 977 for B=1e6
    loss_main_kernel<<<blocks, BLOCK, 0, stream>>>(outp, tgt, acc, B);
    loss_finalize_kernel<<<1, 1, 0, stream>>>(acc, out, B);
}

// Round 6
// 101.592 us; speedup vs baseline: 1.7341x; 1.7341x over previous
//
#include <hip/hip_runtime.h>
#include <hip/hip_bf16.h>
#include <stdint.h>

#define J_JOINTS 17
#define ROW_F 51                         // floats per row per array
#define BLOCK 256
#define TILE_ROWS 32                     // rows per tile buffer; 8 threads/row
#define TILE_F (TILE_ROWS * ROW_F)       // 1632 floats per array per buffer
#define TILE_CHUNKS (TILE_F / 4)         // 408 16B chunks per array per buffer
#define GRID 1536                        // 6 blocks/CU (26 KB LDS each)

__device__ __forceinline__ void gld_lds16(const float* g, float* l) {
    // async global -> LDS, 16B per lane; LDS dest = wave base + lane*16
    __builtin_amdgcn_global_load_lds(
        (const __attribute__((address_space(1))) void*)g,
        (__attribute__((address_space(3))) void*)l,
        16, 0, 0);
}

__global__ __launch_bounds__(BLOCK) void loss_main_kernel(
    const float* __restrict__ outp,   // (B, 17, 3)
    const float* __restrict__ tgt,    // (B, 17, 3)
    double* __restrict__ acc,         // acc[0]=cls_sum, acc[1]=reg_sum
    int B)
{
    __shared__ float so[2][TILE_F];   // 2 x 6528 B
    __shared__ float st[2][TILE_F];   // total 26112 B -> 6 blocks/CU

    const int tid = threadIdx.x;
    const int r8  = tid >> 3;   // local row (0..31)
    const int q   = tid & 7;    // joint pair: joints 2q, 2q+1 (+16 if q==7)

    float cls_acc = 0.0f;
    float reg_acc = 0.0f;

    const int tiles_total = (B + TILE_ROWS - 1) / TILE_ROWS;

    // fast path: full tile, async direct-to-LDS (linear dest required)
    auto stage_async = [&](int row0, int buf) {
        const float* go = outp + row0 * ROW_F;
        const float* gt = tgt  + row0 * ROW_F;
        float* lo = so[buf];
        float* lt = st[buf];
        #pragma unroll
        for (int j = 0; j < 2; ++j) {
            const int i = tid + j * BLOCK;
            if (i < TILE_CHUNKS) {
                gld_lds16(go + i * 4, lo + i * 4);
                gld_lds16(gt + i * 4, lt + i * 4);
            }
        }
    };
    // slow path: partial tile, guarded sync loads (only if B % TILE_ROWS != 0)
    auto stage_sync = [&](int row0, int rows_valid, int buf) {
        const float* go = outp + row0 * ROW_F;
        const float* gt = tgt  + row0 * ROW_F;
        const int nv = rows_valid * ROW_F;
        const int n4 = nv >> 2;
        for (int i = tid; i < n4; i += BLOCK) {
            reinterpret_cast<float4*>(so[buf])[i] = reinterpret_cast<const float4*>(go)[i];
            reinterpret_cast<float4*>(st[buf])[i] = reinterpret_cast<const float4*>(gt)[i];
        }
        const int tb = n4 << 2;
        if (tid < nv - tb) {
            so[buf][tb + tid] = go[tb + tid];
            st[buf][tb + tid] = gt[tb + tid];
        }
    };
    auto stage = [&](int tk, int buf) {
        const int row0 = tk * TILE_ROWS;
        if (row0 + TILE_ROWS <= B) stage_async(row0, buf);
        else                       stage_sync(row0, B - row0, buf);
    };

    // ---- pipeline: stage(t+1) in flight while computing t ----
    int tk  = blockIdx.x;
    int cur = 0;

    if (tk < tiles_total) stage(tk, 0);
    asm volatile("s_waitcnt vmcnt(0)" ::: "memory");
    __syncthreads();

    while (tk < tiles_total) {
        const int tn = tk + GRID;
        if (tn < tiles_total) stage(tn, cur ^ 1);

        // ---- compute buf[cur] from LDS: 8 threads per row ----
        const int rows_valid = min(TILE_ROWS, B - tk * TILE_ROWS);
        float sq = 0.0f;
        float nj = 0.0f;
        if (r8 < rows_valid) {
            const float* lo = so[cur] + r8 * ROW_F + q * 6;
            const float* lt = st[cur] + r8 * ROW_F + q * 6;
            #pragma unroll
            for (int k = 0; k < 2; ++k) {
                const float ox = lo[3*k + 0];
                const float oy = lo[3*k + 1];
                const float oz = lo[3*k + 2];
                const float tx = lt[3*k + 0];
                const float ty = lt[3*k + 1];
                const float tz = lt[3*k + 2];

                const bool gt1 = (tz == 1.0f);
                cls_acc += fmaxf(__logf(gt1 ? oz : (1.0f - oz)), -100.0f);

                const bool keep = (oz >= 0.5f);
                const float d0 = keep ? (ox - tx) : 0.0f;
                const float d1 = keep ? (oy - ty) : 0.0f;
                sq = fmaf(d0, d0, fmaf(d1, d1, sq));
                nj += gt1 ? 1.0f : 0.0f;
            }
            if (q == 7) {   // joint 16: floats 48..50 = 6 past q*6=42
                const float ox = lo[6 + 0];
                const float oy = lo[6 + 1];
                const float oz = lo[6 + 2];
                const float tx = lt[6 + 0];
                const float ty = lt[6 + 1];
                const float tz = lt[6 + 2];

                const bool gt1 = (tz == 1.0f);
                cls_acc += fmaxf(__logf(gt1 ? oz : (1.0f - oz)), -100.0f);

                const bool keep = (oz >= 0.5f);
                const float d0 = keep ? (ox - tx) : 0.0f;
                const float d1 = keep ? (oy - ty) : 0.0f;
                sq = fmaf(d0, d0, fmaf(d1, d1, sq));
                nj += gt1 ? 1.0f : 0.0f;
            }
        }
        // segmented reduce across the 8-lane row group
        sq += __shfl_xor(sq, 1, 64);  nj += __shfl_xor(nj, 1, 64);
        sq += __shfl_xor(sq, 2, 64);  nj += __shfl_xor(nj, 2, 64);
        sq += __shfl_xor(sq, 4, 64);  nj += __shfl_xor(nj, 4, 64);
        if (q == 0 && r8 < rows_valid) {
            reg_acc += __fdividef(0.5f * sq, 1.0f + nj);
        }

        // drain next-tile loads + protect LDS buffers
        asm volatile("s_waitcnt vmcnt(0)" ::: "memory");
        __syncthreads();
        cur ^= 1;
        tk = tn;
    }

    // ---- block reduction ----
    #pragma unroll
    for (int m = 1; m < 64; m <<= 1) {
        cls_acc += __shfl_xor(cls_acc, m, 64);
        reg_acc += __shfl_xor(reg_acc, m, 64);
    }
    __shared__ float s_cls[BLOCK / 64];
    __shared__ float s_reg[BLOCK / 64];
    const int wid = tid >> 6;
    if ((tid & 63) == 0) {
        s_cls[wid] = cls_acc;
        s_reg[wid] = reg_acc;
    }
    __syncthreads();
    if (tid == 0) {
        float c = 0.0f, r = 0.0f;
        #pragma unroll
        for (int w = 0; w < BLOCK / 64; ++w) { c += s_cls[w]; r += s_reg[w]; }
        atomicAdd(&acc[0], (double)c);
        atomicAdd(&acc[1], (double)r);
    }
}

__global__ void loss_finalize_kernel(const double* __restrict__ acc,
                                     float* __restrict__ out, int B)
{
    const double cls_sum = acc[0];
    const double reg_sum = acc[1];
    const double loss_class = -cls_sum / ((double)B * (double)J_JOINTS);
    const double loss_reg   = reg_sum / (double)B;
    out[0] = (float)(loss_class + loss_reg);
}

extern "C" void kernel_launch(void* const* d_in, const int* in_sizes, int n_in,
                              void* d_out, int out_size, void* d_ws, size_t ws_size,
                              hipStream_t stream) {
    const float* outp = (const float*)d_in[0];
    const float* tgt  = (const float*)d_in[1];
    float* out = (float*)d_out;
    const int B = in_sizes[0] / (J_JOINTS * 3);

    double* acc = (double*)d_ws;
    hipMemsetAsync(acc, 0, 2 * sizeof(double), stream);

    loss_main_kernel<<<GRID, BLOCK, 0, stream>>>(outp, tgt, acc, B);
    loss_finalize_kernel<<<1, 1, 0, stream>>>(acc, out, B);
}

// Round 7
// 92.713 us; speedup vs baseline: 1.9001x; 1.0958x over previous
//
#include <hip/hip_runtime.h>
#include <hip/hip_bf16.h>
#include <stdint.h>

#define J_JOINTS 17
#define ROW_F 51                         // floats per row per array
#define BLOCK 256
#define TILE_ROWS 32                     // rows per tile buffer; 8 threads/row
#define TILE_F (TILE_ROWS * ROW_F)       // 1632 floats per array per buffer
#define TILE_CHUNKS (TILE_F / 4)         // 408 16B chunks per array per buffer
#define NBUF 4                           // ring depth
#define CHUNKS_PER_WAVE 102              // 408 / 4 waves -> exactly 2 instrs/wave/array
#define GRID 768                         // 3 blocks/CU (52 KB LDS each)

__device__ __forceinline__ void gld_lds16(const float* g, float* l) {
    // async global -> LDS, 16B per lane; LDS dest = wave-uniform base + lane*16
    __builtin_amdgcn_global_load_lds(
        (const __attribute__((address_space(1))) void*)g,
        (__attribute__((address_space(3))) void*)l,
        16, 0, 0);
}

__global__ __launch_bounds__(BLOCK) void loss_main_kernel(
    const float* __restrict__ outp,   // (B, 17, 3)
    const float* __restrict__ tgt,    // (B, 17, 3)
    double* __restrict__ acc,         // acc[0]=cls_sum, acc[1]=reg_sum
    int B)
{
    __shared__ float so[NBUF][TILE_F];   // 4 x 6528 B
    __shared__ float st[NBUF][TILE_F];   // total 52224 B -> 3 blocks/CU

    const int tid = threadIdx.x;
    const int wv  = tid >> 6;   // wave 0..3
    const int ln  = tid & 63;
    const int r8  = tid >> 3;   // local row (0..31)
    const int q   = tid & 7;    // joint pair: joints 2q, 2q+1 (+16 if q==7)

    float cls_acc = 0.0f;
    float reg_acc = 0.0f;

    const int tiles_full = B / TILE_ROWS;            // full tiles only
    // this block's tiles: t_i = blockIdx.x + i*GRID, i in [0, nt)
    const int nt = (tiles_full > (int)blockIdx.x)
                 ? (tiles_full - (int)blockIdx.x + GRID - 1) / GRID : 0;

    // stage: every wave issues EXACTLY 4 VMEM instrs (2 per array)
    auto stage = [&](int i) {
        const int tile = (int)blockIdx.x + i * GRID;
        const int buf  = i & (NBUF - 1);
        const float* go = outp + tile * TILE_F;
        const float* gt = tgt  + tile * TILE_F;
        const int c0 = wv * CHUNKS_PER_WAVE + ln;     // < 408 always
        gld_lds16(go + c0 * 4, &so[buf][c0 * 4]);
        gld_lds16(gt + c0 * 4, &st[buf][c0 * 4]);
        const int c1 = c0 + 64;
        if (ln < CHUNKS_PER_WAVE - 64) {              // 38 lanes
            gld_lds16(go + c1 * 4, &so[buf][c1 * 4]);
            gld_lds16(gt + c1 * 4, &st[buf][c1 * 4]);
        }
    };

    // ---- prologue: fill the ring ----
    if (nt > 0) stage(0);
    if (nt > 1) stage(1);
    if (nt > 2) stage(2);

    for (int i = 0; i < nt; ++i) {
        if (i + 3 < nt) stage(i + 3);

        // wait for OWN tile-i loads: 4 instrs per in-flight newer tile
        const int newer = min(nt - 1 - i, 3);
        if      (newer == 3) asm volatile("s_waitcnt vmcnt(12)" ::: "memory");
        else if (newer == 2) asm volatile("s_waitcnt vmcnt(8)"  ::: "memory");
        else if (newer == 1) asm volatile("s_waitcnt vmcnt(4)"  ::: "memory");
        else                 asm volatile("s_waitcnt vmcnt(0)"  ::: "memory");
        __builtin_amdgcn_s_barrier();        // all waves' tile-i stages done
        __builtin_amdgcn_sched_barrier(0);

        // ---- compute buf from LDS: 8 threads per row ----
        const int buf = i & (NBUF - 1);
        float sq = 0.0f;
        float nj = 0.0f;
        {
            const float* lo = &so[buf][r8 * ROW_F + q * 6];
            const float* lt = &st[buf][r8 * ROW_F + q * 6];
            #pragma unroll
            for (int k = 0; k < 2; ++k) {
                const float ox = lo[3*k + 0];
                const float oy = lo[3*k + 1];
                const float oz = lo[3*k + 2];
                const float tx = lt[3*k + 0];
                const float ty = lt[3*k + 1];
                const float tz = lt[3*k + 2];

                const bool gt1 = (tz == 1.0f);
                cls_acc += fmaxf(__logf(gt1 ? oz : (1.0f - oz)), -100.0f);

                const bool keep = (oz >= 0.5f);
                const float d0 = keep ? (ox - tx) : 0.0f;
                const float d1 = keep ? (oy - ty) : 0.0f;
                sq = fmaf(d0, d0, fmaf(d1, d1, sq));
                nj += gt1 ? 1.0f : 0.0f;
            }
            if (q == 7) {   // joint 16: floats 48..50 = 6 past q*6=42
                const float ox = lo[6 + 0];
                const float oy = lo[6 + 1];
                const float oz = lo[6 + 2];
                const float tx = lt[6 + 0];
                const float ty = lt[6 + 1];
                const float tz = lt[6 + 2];

                const bool gt1 = (tz == 1.0f);
                cls_acc += fmaxf(__logf(gt1 ? oz : (1.0f - oz)), -100.0f);

                const bool keep = (oz >= 0.5f);
                const float d0 = keep ? (ox - tx) : 0.0f;
                const float d1 = keep ? (oy - ty) : 0.0f;
                sq = fmaf(d0, d0, fmaf(d1, d1, sq));
                nj += gt1 ? 1.0f : 0.0f;
            }
        }
        // segmented reduce across the 8-lane row group
        sq += __shfl_xor(sq, 1, 64);  nj += __shfl_xor(nj, 1, 64);
        sq += __shfl_xor(sq, 2, 64);  nj += __shfl_xor(nj, 2, 64);
        sq += __shfl_xor(sq, 4, 64);  nj += __shfl_xor(nj, 4, 64);
        if (q == 0) {
            reg_acc += __fdividef(0.5f * sq, 1.0f + nj);
        }

        __builtin_amdgcn_sched_barrier(0);
        __builtin_amdgcn_s_barrier();        // buf free for reuse next iter
    }

    // ---- generic tail rows (B % TILE_ROWS != 0): after ring, outstanding==0 ----
    const int tail0 = tiles_full * TILE_ROWS;
    if (blockIdx.x == 0 && tid < (B - tail0)) {
        const int b = tail0 + tid;
        float sq = 0.f, nj = 0.f;
        for (int j = 0; j < J_JOINTS; ++j) {
            const int base = b * ROW_F + 3*j;
            const float ox = outp[base + 0];
            const float oy = outp[base + 1];
            const float oz = outp[base + 2];
            const float tx = tgt[base + 0];
            const float ty = tgt[base + 1];
            const float tz = tgt[base + 2];
            const bool gt1 = (tz == 1.0f);
            cls_acc += fmaxf(__logf(gt1 ? oz : (1.0f - oz)), -100.0f);
            const bool keep = (oz >= 0.5f);
            const float d0 = keep ? (ox - tx) : 0.0f;
            const float d1 = keep ? (oy - ty) : 0.0f;
            sq = fmaf(d0, d0, fmaf(d1, d1, sq));
            nj += gt1 ? 1.0f : 0.0f;
        }
        reg_acc += __fdividef(0.5f * sq, 1.0f + nj);
    }

    // ---- block reduction ----
    #pragma unroll
    for (int m = 1; m < 64; m <<= 1) {
        cls_acc += __shfl_xor(cls_acc, m, 64);
        reg_acc += __shfl_xor(reg_acc, m, 64);
    }
    __shared__ float s_cls[BLOCK / 64];
    __shared__ float s_reg[BLOCK / 64];
    if (ln == 0) {
        s_cls[wv] = cls_acc;
        s_reg[wv] = reg_acc;
    }
    __syncthreads();
    if (tid == 0) {
        float c = 0.0f, r = 0.0f;
        #pragma unroll
        for (int w = 0; w < BLOCK / 64; ++w) { c += s_cls[w]; r += s_reg[w]; }
        atomicAdd(&acc[0], (double)c);
        atomicAdd(&acc[1], (double)r);
    }
}

__global__ void loss_finalize_kernel(const double* __restrict__ acc,
                                     float* __restrict__ out, int B)
{
    const double cls_sum = acc[0];
    const double reg_sum = acc[1];
    const double loss_class = -cls_sum / ((double)B * (double)J_JOINTS);
    const double loss_reg   = reg_sum / (double)B;
    out[0] = (float)(loss_class + loss_reg);
}

extern "C" void kernel_launch(void* const* d_in, const int* in_sizes, int n_in,
                              void* d_out, int out_size, void* d_ws, size_t ws_size,
                              hipStream_t stream) {
    const float* outp = (const float*)d_in[0];
    const float* tgt  = (const float*)d_in[1];
    float* out = (float*)d_out;
    const int B = in_sizes[0] / (J_JOINTS * 3);

    double* acc = (double*)d_ws;
    hipMemsetAsync(acc, 0, 2 * sizeof(double), stream);

    loss_main_kernel<<<GRID, BLOCK, 0, stream>>>(outp, tgt, acc, B);
    loss_finalize_kernel<<<1, 1, 0, stream>>>(acc, out, B);
}